// Round 1
// baseline (161.071 us; speedup 1.0000x reference)
//
#include <hip/hip_runtime.h>
#include <hip/hip_fp16.h>
#include <math.h>

#define NG 2048
#define IMG_W 128
#define IMG_H 128
#define NPIX (IMG_W * IMG_H)
#define L2E 1.4426950408889634f

// 32-byte packed gaussian record = 2 x float4 for ds_read_b128 staging.
// A = -0.5*log2e*conic_a, B = -log2e*conic_b, C = -0.5*log2e*conic_c
// so power_log2 = A*dx^2 + B*dx*dy + C*dy^2 and g = exp2(min(power_log2,0)).
// f0 = (u, v, A, B); f1 = (C, alpha_f32, (cr,cg) half2, (cb, r2) half2)
// r2 = cull radius^2: skip gaussian for a tile if min dist^2 > r2
// (power_log2 <= -0.5*L2E*lam_min*d^2; THR=24 -> r2 = 2*24/(L2E*lam_min)).
struct __align__(16) PG {
    float u, v, A, B;
    float C, alpha;
    unsigned int rg;    // half2 (cr, cg)
    unsigned int b_r2;  // half2 (cb, r2)
};

// Bitwise-deterministic camera-z: explicit fmaf chain so every call site
// (own gaussian AND the rank scan) produces identical bits -> rank is a
// valid stable permutation.
__device__ __forceinline__ float cam_z(float mx, float my, float mz,
                                       float R20, float R21, float R22,
                                       float t2)
{
    return fmaf(R20, mx, fmaf(R21, my, fmaf(R22, mz, t2)));
}

// ---------------------------------------------------------------------------
// Kernel 1 (fused prep + rank + scatter): one wave per gaussian.
// All 64 lanes redundantly compute the wave's gaussian projection (wave-
// uniform work, ~free), then cooperatively count rank[g] = #{h : z[h]<z[g]
// or (z[h]==z[g] and h<g)} by recomputing z[h] inline from mean (identical
// fmaf chain => bitwise-consistent across waves). Lanes 0/1 scatter the
// 32-byte record to gsorted[rank]. Wave 0 of block 0 also zeroes the
// per-tile combine counters (workspace is poisoned every iteration).
// ---------------------------------------------------------------------------
__global__ __launch_bounds__(256) void prep_rank_kernel(
    const float* __restrict__ mean, const float* __restrict__ qvec,
    const float* __restrict__ svec_raw, const float* __restrict__ color_raw,
    const float* __restrict__ alpha_raw, const float* __restrict__ viewmat,
    const float* __restrict__ intrins, PG* __restrict__ gsorted,
    unsigned int* __restrict__ tile_cnt)
{
    const int g = (blockIdx.x * 256 + threadIdx.x) >> 6; // gaussian id
    const int lane = threadIdx.x & 63;

    if (blockIdx.x == 0 && threadIdx.x < 64) tile_cnt[threadIdx.x] = 0;

    const float fx = intrins[0], fy = intrins[1], cx = intrins[2], cy = intrins[3];
    const float R00 = viewmat[0], R01 = viewmat[1], R02 = viewmat[2],  t0 = viewmat[3];
    const float R10 = viewmat[4], R11 = viewmat[5], R12 = viewmat[6],  t1 = viewmat[7];
    const float R20 = viewmat[8], R21 = viewmat[9], R22 = viewmat[10], t2 = viewmat[11];

    float mx = mean[g * 3 + 0], my = mean[g * 3 + 1], mz = mean[g * 3 + 2];
    float x = R00 * mx + R01 * my + R02 * mz + t0;
    float y = R10 * mx + R11 * my + R12 * mz + t1;
    float z = cam_z(mx, my, mz, R20, R21, R22, t2);
    float zc = fmaxf(z, 0.001f);

    float qw = qvec[g * 4 + 0], qx = qvec[g * 4 + 1];
    float qy = qvec[g * 4 + 2], qz = qvec[g * 4 + 3];
    float qn = rsqrtf(qw * qw + qx * qx + qy * qy + qz * qz);
    qw *= qn; qx *= qn; qy *= qn; qz *= qn;
    float Rq00 = 1.f - 2.f * (qy * qy + qz * qz), Rq01 = 2.f * (qx * qy - qw * qz), Rq02 = 2.f * (qx * qz + qw * qy);
    float Rq10 = 2.f * (qx * qy + qw * qz), Rq11 = 1.f - 2.f * (qx * qx + qz * qz), Rq12 = 2.f * (qy * qz - qw * qx);
    float Rq20 = 2.f * (qx * qz - qw * qy), Rq21 = 2.f * (qy * qz + qw * qx), Rq22 = 1.f - 2.f * (qx * qx + qy * qy);

    float s0 = expf(svec_raw[g * 3 + 0]);
    float s1 = expf(svec_raw[g * 3 + 1]);
    float s2 = expf(svec_raw[g * 3 + 2]);
    float M00 = Rq00 * s0, M01 = Rq01 * s1, M02 = Rq02 * s2;
    float M10 = Rq10 * s0, M11 = Rq11 * s1, M12 = Rq12 * s2;
    float M20 = Rq20 * s0, M21 = Rq21 * s1, M22 = Rq22 * s2;

    float iz = 1.0f / zc;
    float J00 = fx * iz, J02 = -fx * x * iz * iz;
    float J11 = fy * iz, J12 = -fy * y * iz * iz;
    float T00 = J00 * R00 + J02 * R20;
    float T01 = J00 * R01 + J02 * R21;
    float T02 = J00 * R02 + J02 * R22;
    float T10 = J11 * R10 + J12 * R20;
    float T11 = J11 * R11 + J12 * R21;
    float T12 = J11 * R12 + J12 * R22;
    float TM00 = T00 * M00 + T01 * M10 + T02 * M20;
    float TM01 = T00 * M01 + T01 * M11 + T02 * M21;
    float TM02 = T00 * M02 + T01 * M12 + T02 * M22;
    float TM10 = T10 * M00 + T11 * M10 + T12 * M20;
    float TM11 = T10 * M01 + T11 * M11 + T12 * M21;
    float TM12 = T10 * M02 + T11 * M12 + T12 * M22;
    float a = TM00 * TM00 + TM01 * TM01 + TM02 * TM02 + 0.3f;
    float b = TM00 * TM10 + TM01 * TM11 + TM02 * TM12;
    float c = TM10 * TM10 + TM11 * TM11 + TM12 * TM12 + 0.3f;
    float det = a * c - b * b;
    float det_safe = fmaxf(det, 1e-8f);
    float inv_det = 1.0f / det_safe;
    bool valid = (z > 0.2f) && (det > 0.0f);
    float alpha = 1.0f / (1.0f + expf(-alpha_raw[g]));

    float conic_a = c * inv_det;
    float conic_b = -b * inv_det;
    float conic_c = a * inv_det;

    // cull radius^2 from conic lambda_min (THR = 24 log2-units; slack 1.05x)
    float half_tr = 0.5f * (conic_a + conic_c);
    float half_df = 0.5f * (conic_a - conic_c);
    float lam_min = half_tr - sqrtf(half_df * half_df + conic_b * conic_b);
    float r2 = (lam_min > 1e-20f) ? (1.05f * 2.0f * 24.0f / (L2E * lam_min)) : 3.0e38f;
    if (!valid) r2 = -1.0f; // skip always

    PG pg;
    pg.u = fx * x * iz + cx;
    pg.v = fy * y * iz + cy;
    pg.A = -0.5f * L2E * conic_a;
    pg.B = -L2E * conic_b;
    pg.C = -0.5f * L2E * conic_c;
    pg.alpha = alpha;
    float cr  = 1.0f / (1.0f + expf(-color_raw[g * 3 + 0]));
    float cg  = 1.0f / (1.0f + expf(-color_raw[g * 3 + 1]));
    float cbl = 1.0f / (1.0f + expf(-color_raw[g * 3 + 2]));
    __half2 hrg = __floats2half2_rn(cr, cg);
    pg.rg = *reinterpret_cast<unsigned int*>(&hrg);
    // (cb, r2) as half2; r2 > 65504 rounds to +inf -> always-keep (correctly
    // conservative); r2 = -1 -> always-skip (invalid gaussian).
    __half2 hbr = __halves2half2(__float2half_rn(cbl), __float2half_rn(r2));
    pg.b_r2 = *reinterpret_cast<unsigned int*>(&hbr);

    // ---- rank scan: lanes cooperatively count over all NG gaussians ----
    const float zg = z;
    int cnt = 0;
#pragma unroll
    for (int k = 0; k < NG / 64; ++k) {
        int h = k * 64 + lane;
        float hx = mean[h * 3 + 0], hy = mean[h * 3 + 1], hz = mean[h * 3 + 2];
        float zh = cam_z(hx, hy, hz, R20, R21, R22, t2);
        cnt += ((zh < zg) || ((zh == zg) && (h < g))) ? 1 : 0;
    }
#pragma unroll
    for (int off = 32; off >= 1; off >>= 1)
        cnt += __shfl_down(cnt, off);
    int rank = __shfl(cnt, 0);

    if (lane < 2) {
        const float4* src = reinterpret_cast<const float4*>(&pg);
        ((float4*)(gsorted + rank))[lane] = src[lane];
    }
}

// ---------------------------------------------------------------------------
// Kernel 2: segmented compositing with per-tile circle culling + fused
// in-order combine (last-block-done pattern).
// Block = 64 threads = one wave = 16x16 pixel tile, 4 pixels/thread (column).
// Cull: lane i tests gaussian base+i vs tile box (verdict is tile-uniform),
// __ballot -> uniform 64-bit mask, ctz-walk preserves front-to-back order.
// After writing its partial, each block does release-fence + atomicAdd on
// the per-tile counter; the block that sees NSEG-1 acquire-fences and
// composes all NSEG partials in segment order (deterministic), adds bg,
// writes the output pixels. grid (8, 8, NSEG).
// ---------------------------------------------------------------------------
template <int NSEG>
__global__ __launch_bounds__(64) void composite_kernel(
    const PG* __restrict__ gsorted, float4* __restrict__ partial,
    unsigned int* __restrict__ tile_cnt, const float* __restrict__ bg,
    float* __restrict__ out)
{
    constexpr int SEG = NG / NSEG;
    __shared__ float4 sg[SEG * 2];
    const int t = threadIdx.x;
    const int seg = blockIdx.z;
    const int col = blockIdx.x * 16 + (t & 15);
    const int row0 = blockIdx.y * 16 + (t >> 4) * 4;

    const float4* src = (const float4*)(gsorted + seg * SEG);
#pragma unroll
    for (int i = t; i < SEG * 2; i += 64) sg[i] = src[i];
    __syncthreads();

    // tile pixel-center bounds
    const float x0 = blockIdx.x * 16 + 0.5f, x1 = x0 + 15.0f;
    const float y0 = blockIdx.y * 16 + 0.5f, y1 = y0 + 15.0f;

    const float fpx = col + 0.5f;
    const float fpy0 = row0 + 0.5f;
    float T0 = 1.f, T1 = 1.f, T2 = 1.f, T3 = 1.f;
    float Cr0 = 0.f, Cg0 = 0.f, Cb0 = 0.f;
    float Cr1 = 0.f, Cg1 = 0.f, Cb1 = 0.f;
    float Cr2 = 0.f, Cg2 = 0.f, Cb2 = 0.f;
    float Cr3 = 0.f, Cg3 = 0.f, Cb3 = 0.f;

    for (int base = 0; base < SEG; base += 64) {
        // lane t tests gaussian base+t against the tile
        float4 g0 = sg[2 * (base + t) + 0];
        float4 g1 = sg[2 * (base + t) + 1];
        union { float f; __half2 h; } ubr; ubr.f = g1.w;
        float r2 = __half2float(__high2half(ubr.h));
        float dxm = fmaxf(0.f, fmaxf(x0 - g0.x, g0.x - x1));
        float dym = fmaxf(0.f, fmaxf(y0 - g0.y, g0.y - y1));
        bool keep = (dxm * dxm + dym * dym) <= r2;
        unsigned long long mask = __ballot(keep);

        while (mask) {
            int i = base + (int)__builtin_ctzll(mask);
            mask &= (mask - 1);
            float4 f0 = sg[2 * i + 0];
            float4 f1 = sg[2 * i + 1];
            float dx = fpx - f0.x;
            float adx2 = f0.z * dx * dx;
            float bdx = f0.w * dx;
            float alpha = f1.y;
            union { float f; __half2 h; } urg; urg.f = f1.z;
            union { float f; __half2 h; } ubl; ubl.f = f1.w;
            float cr = __half2float(__low2half(urg.h));
            float cg = __half2float(__high2half(urg.h));
            float cb = __half2float(__low2half(ubl.h));

            float dy, p, gv, a, w;

            dy = fpy0 - f0.y;
            p = fminf(fmaf(dy, fmaf(f1.x, dy, bdx), adx2), 0.f);
            gv = exp2f(p);
            a = fminf(0.99f, alpha * gv);
            w = a * T0;
            Cr0 = fmaf(w, cr, Cr0); Cg0 = fmaf(w, cg, Cg0); Cb0 = fmaf(w, cb, Cb0);
            T0 = fmaf(-a, T0, T0);

            dy = (fpy0 + 1.f) - f0.y;
            p = fminf(fmaf(dy, fmaf(f1.x, dy, bdx), adx2), 0.f);
            gv = exp2f(p);
            a = fminf(0.99f, alpha * gv);
            w = a * T1;
            Cr1 = fmaf(w, cr, Cr1); Cg1 = fmaf(w, cg, Cg1); Cb1 = fmaf(w, cb, Cb1);
            T1 = fmaf(-a, T1, T1);

            dy = (fpy0 + 2.f) - f0.y;
            p = fminf(fmaf(dy, fmaf(f1.x, dy, bdx), adx2), 0.f);
            gv = exp2f(p);
            a = fminf(0.99f, alpha * gv);
            w = a * T2;
            Cr2 = fmaf(w, cr, Cr2); Cg2 = fmaf(w, cg, Cg2); Cb2 = fmaf(w, cb, Cb2);
            T2 = fmaf(-a, T2, T2);

            dy = (fpy0 + 3.f) - f0.y;
            p = fminf(fmaf(dy, fmaf(f1.x, dy, bdx), adx2), 0.f);
            gv = exp2f(p);
            a = fminf(0.99f, alpha * gv);
            w = a * T3;
            Cr3 = fmaf(w, cr, Cr3); Cg3 = fmaf(w, cg, Cg3); Cb3 = fmaf(w, cb, Cb3);
            T3 = fmaf(-a, T3, T3);
        }
    }

    float4* dst = partial + (size_t)seg * NPIX + row0 * IMG_W + col;
    dst[0 * IMG_W] = make_float4(Cr0, Cg0, Cb0, T0);
    dst[1 * IMG_W] = make_float4(Cr1, Cg1, Cb1, T1);
    dst[2 * IMG_W] = make_float4(Cr2, Cg2, Cb2, T2);
    dst[3 * IMG_W] = make_float4(Cr3, Cg3, Cb3, T3);

    // ---- fused combine: last block for this tile composes all segments ----
    __threadfence();                        // release partial writes
    int old;
    const int tile = blockIdx.y * 8 + blockIdx.x;
    if (t == 0) old = (int)atomicAdd(&tile_cnt[tile], 1u);
    old = __shfl(old, 0);
    if (old == NSEG - 1) {
        __threadfence();                    // acquire other blocks' partials
        const float bg0 = bg[0], bg1 = bg[1], bg2 = bg[2];
        const int pixbase = row0 * IMG_W + col;
#pragma unroll
        for (int r = 0; r < 4; ++r) {
            const int pix = pixbase + r * IMG_W;
            float T = 1.f, Cr = 0.f, Cg = 0.f, Cb = 0.f;
#pragma unroll
            for (int s = 0; s < NSEG; ++s) {
                float4 p = partial[(size_t)s * NPIX + pix];
                Cr = fmaf(T, p.x, Cr);
                Cg = fmaf(T, p.y, Cg);
                Cb = fmaf(T, p.z, Cb);
                T *= p.w;
            }
            out[pix * 3 + 0] = Cr + T * bg0;
            out[pix * 3 + 1] = Cg + T * bg1;
            out[pix * 3 + 2] = Cb + T * bg2;
        }
    }
}

template <int NSEG>
static void launch_pipeline(const float* mean, const float* qvec,
                            const float* svec_raw, const float* color_raw,
                            const float* alpha_raw, const float* bg,
                            const float* viewmat, const float* intrins,
                            float* out, char* ws, hipStream_t stream)
{
    PG* gsorted = (PG*)ws;                                     // 64 KiB
    float4* partial = (float4*)(ws + NG * sizeof(PG));         // NSEG*256 KiB
    unsigned int* tile_cnt =
        (unsigned int*)(ws + NG * sizeof(PG) + (size_t)NSEG * NPIX * sizeof(float4));

    hipLaunchKernelGGL(prep_rank_kernel, dim3(NG * 64 / 256), dim3(256), 0,
                       stream, mean, qvec, svec_raw, color_raw, alpha_raw,
                       viewmat, intrins, gsorted, tile_cnt);
    hipLaunchKernelGGL((composite_kernel<NSEG>), dim3(8, 8, NSEG), dim3(64),
                       0, stream, gsorted, partial, tile_cnt, bg, out);
}

extern "C" void kernel_launch(void* const* d_in, const int* in_sizes, int n_in,
                              void* d_out, int out_size, void* d_ws, size_t ws_size,
                              hipStream_t stream)
{
    const float* mean      = (const float*)d_in[0];
    const float* qvec      = (const float*)d_in[1];
    const float* svec_raw  = (const float*)d_in[2];
    const float* color_raw = (const float*)d_in[3];
    const float* alpha_raw = (const float*)d_in[4];
    const float* bg        = (const float*)d_in[5];
    const float* viewmat   = (const float*)d_in[6];
    const float* intrins   = (const float*)d_in[7];
    char* ws = (char*)d_ws;
    float* out = (float*)d_out;

    const size_t fixed = NG * sizeof(PG) + 64 * sizeof(unsigned int);
    if (ws_size >= fixed + (size_t)32 * NPIX * sizeof(float4)) {
        launch_pipeline<32>(mean, qvec, svec_raw, color_raw, alpha_raw, bg,
                            viewmat, intrins, out, ws, stream);
    } else if (ws_size >= fixed + (size_t)16 * NPIX * sizeof(float4)) {
        launch_pipeline<16>(mean, qvec, svec_raw, color_raw, alpha_raw, bg,
                            viewmat, intrins, out, ws, stream);
    } else {
        launch_pipeline<8>(mean, qvec, svec_raw, color_raw, alpha_raw, bg,
                           viewmat, intrins, out, ws, stream);
    }
}

// Round 2
// 114.494 us; speedup vs baseline: 1.4068x; 1.4068x over previous
//
#include <hip/hip_runtime.h>
#include <hip/hip_fp16.h>
#include <math.h>

#define NG 2048
#define IMG_W 128
#define IMG_H 128
#define NPIX (IMG_W * IMG_H)
#define L2E 1.4426950408889634f

// 32-byte packed gaussian record = 2 x float4.
// A = -0.5*log2e*conic_a, B = -log2e*conic_b, C = -0.5*log2e*conic_c
// so power_log2 = A*dx^2 + B*dx*dy + C*dy^2 and g = exp2(min(power_log2,0)).
// f0 = (u, v, A, B); f1 = (C, alpha_f32, (cr,cg) half2, (cb, r2) half2)
// r2 = cull radius^2: skip gaussian for a tile if min dist^2 > r2.
struct __align__(16) PG {
    float u, v, A, B;
    float C, alpha;
    unsigned int rg;    // half2 (cr, cg)
    unsigned int b_r2;  // half2 (cb, r2)
};

// Bitwise-deterministic camera-z: identical fmaf chain at every call site
// (own gaussian AND the rank scan) -> rank is a valid stable permutation.
__device__ __forceinline__ float cam_z(float mx, float my, float mz,
                                       float R20, float R21, float R22,
                                       float t2)
{
    return fmaf(R20, mx, fmaf(R21, my, fmaf(R22, mz, t2)));
}

// ---------------------------------------------------------------------------
// Kernel 1 (fused prep + rank + scatter): one wave per gaussian.
// All 64 lanes redundantly compute the wave's gaussian projection (wave-
// uniform, ~free), then cooperatively count
//   rank[g] = #{h : z[h] < z[g] or (z[h]==z[g] and h<g)}
// by recomputing z[h] inline from mean via float4 loads (4 gaussians per
// lane-iteration; identical fmaf chain => bitwise-consistent across waves).
// Lanes 0/1 scatter the 32-byte record to gsorted[rank].
// ---------------------------------------------------------------------------
__global__ __launch_bounds__(256) void prep_rank_kernel(
    const float* __restrict__ mean, const float* __restrict__ qvec,
    const float* __restrict__ svec_raw, const float* __restrict__ color_raw,
    const float* __restrict__ alpha_raw, const float* __restrict__ viewmat,
    const float* __restrict__ intrins, PG* __restrict__ gsorted)
{
    const int g = (blockIdx.x * 256 + threadIdx.x) >> 6; // gaussian id
    const int lane = threadIdx.x & 63;

    const float fx = intrins[0], fy = intrins[1], cx = intrins[2], cy = intrins[3];
    const float R00 = viewmat[0], R01 = viewmat[1], R02 = viewmat[2],  t0 = viewmat[3];
    const float R10 = viewmat[4], R11 = viewmat[5], R12 = viewmat[6],  t1 = viewmat[7];
    const float R20 = viewmat[8], R21 = viewmat[9], R22 = viewmat[10], t2 = viewmat[11];

    float mx = mean[g * 3 + 0], my = mean[g * 3 + 1], mz = mean[g * 3 + 2];
    float x = R00 * mx + R01 * my + R02 * mz + t0;
    float y = R10 * mx + R11 * my + R12 * mz + t1;
    float z = cam_z(mx, my, mz, R20, R21, R22, t2);
    float zc = fmaxf(z, 0.001f);

    float qw = qvec[g * 4 + 0], qx = qvec[g * 4 + 1];
    float qy = qvec[g * 4 + 2], qz = qvec[g * 4 + 3];
    float qn = rsqrtf(qw * qw + qx * qx + qy * qy + qz * qz);
    qw *= qn; qx *= qn; qy *= qn; qz *= qn;
    float Rq00 = 1.f - 2.f * (qy * qy + qz * qz), Rq01 = 2.f * (qx * qy - qw * qz), Rq02 = 2.f * (qx * qz + qw * qy);
    float Rq10 = 2.f * (qx * qy + qw * qz), Rq11 = 1.f - 2.f * (qx * qx + qz * qz), Rq12 = 2.f * (qy * qz - qw * qx);
    float Rq20 = 2.f * (qx * qz - qw * qy), Rq21 = 2.f * (qy * qz + qw * qx), Rq22 = 1.f - 2.f * (qx * qx + qy * qy);

    float s0 = expf(svec_raw[g * 3 + 0]);
    float s1 = expf(svec_raw[g * 3 + 1]);
    float s2 = expf(svec_raw[g * 3 + 2]);
    float M00 = Rq00 * s0, M01 = Rq01 * s1, M02 = Rq02 * s2;
    float M10 = Rq10 * s0, M11 = Rq11 * s1, M12 = Rq12 * s2;
    float M20 = Rq20 * s0, M21 = Rq21 * s1, M22 = Rq22 * s2;

    float iz = 1.0f / zc;
    float J00 = fx * iz, J02 = -fx * x * iz * iz;
    float J11 = fy * iz, J12 = -fy * y * iz * iz;
    float T00 = J00 * R00 + J02 * R20;
    float T01 = J00 * R01 + J02 * R21;
    float T02 = J00 * R02 + J02 * R22;
    float T10 = J11 * R10 + J12 * R20;
    float T11 = J11 * R11 + J12 * R21;
    float T12 = J11 * R12 + J12 * R22;
    float TM00 = T00 * M00 + T01 * M10 + T02 * M20;
    float TM01 = T00 * M01 + T01 * M11 + T02 * M21;
    float TM02 = T00 * M02 + T01 * M12 + T02 * M22;
    float TM10 = T10 * M00 + T11 * M10 + T12 * M20;
    float TM11 = T10 * M01 + T11 * M11 + T12 * M21;
    float TM12 = T10 * M02 + T11 * M12 + T12 * M22;
    float a = TM00 * TM00 + TM01 * TM01 + TM02 * TM02 + 0.3f;
    float b = TM00 * TM10 + TM01 * TM11 + TM02 * TM12;
    float c = TM10 * TM10 + TM11 * TM11 + TM12 * TM12 + 0.3f;
    float det = a * c - b * b;
    float det_safe = fmaxf(det, 1e-8f);
    float inv_det = 1.0f / det_safe;
    bool valid = (z > 0.2f) && (det > 0.0f);
    float alpha = 1.0f / (1.0f + expf(-alpha_raw[g]));

    float conic_a = c * inv_det;
    float conic_b = -b * inv_det;
    float conic_c = a * inv_det;

    // cull radius^2 from conic lambda_min (THR = 24 log2-units; slack 1.05x)
    float half_tr = 0.5f * (conic_a + conic_c);
    float half_df = 0.5f * (conic_a - conic_c);
    float lam_min = half_tr - sqrtf(half_df * half_df + conic_b * conic_b);
    float r2 = (lam_min > 1e-20f) ? (1.05f * 2.0f * 24.0f / (L2E * lam_min)) : 3.0e38f;
    if (!valid) r2 = -1.0f; // skip always

    PG pg;
    pg.u = fx * x * iz + cx;
    pg.v = fy * y * iz + cy;
    pg.A = -0.5f * L2E * conic_a;
    pg.B = -L2E * conic_b;
    pg.C = -0.5f * L2E * conic_c;
    pg.alpha = alpha;
    float cr  = 1.0f / (1.0f + expf(-color_raw[g * 3 + 0]));
    float cg  = 1.0f / (1.0f + expf(-color_raw[g * 3 + 1]));
    float cbl = 1.0f / (1.0f + expf(-color_raw[g * 3 + 2]));
    __half2 hrg = __floats2half2_rn(cr, cg);
    pg.rg = *reinterpret_cast<unsigned int*>(&hrg);
    // (cb, r2) as half2; r2 > 65504 rounds to +inf -> always-keep (correctly
    // conservative); r2 = -1 -> always-skip (invalid gaussian).
    __half2 hbr = __halves2half2(__float2half_rn(cbl), __float2half_rn(r2));
    pg.b_r2 = *reinterpret_cast<unsigned int*>(&hbr);

    // ---- rank scan: 4 gaussians per lane-iteration via 3 float4 loads ----
    const float4* m4 = (const float4*)mean;
    const float zg = z;
    int cnt = 0;
#pragma unroll
    for (int k = 0; k < NG / 256; ++k) {
        int q = k * 64 + lane;     // quad id: gaussians 4q .. 4q+3
        int h0 = q * 4;
        float4 aa = m4[q * 3 + 0];
        float4 bb = m4[q * 3 + 1];
        float4 cc = m4[q * 3 + 2];
        float z0 = cam_z(aa.x, aa.y, aa.z, R20, R21, R22, t2);
        float z1 = cam_z(aa.w, bb.x, bb.y, R20, R21, R22, t2);
        float z2 = cam_z(bb.z, bb.w, cc.x, R20, R21, R22, t2);
        float z3 = cam_z(cc.y, cc.z, cc.w, R20, R21, R22, t2);
        cnt += ((z0 < zg) || ((z0 == zg) && (h0 + 0 < g))) ? 1 : 0;
        cnt += ((z1 < zg) || ((z1 == zg) && (h0 + 1 < g))) ? 1 : 0;
        cnt += ((z2 < zg) || ((z2 == zg) && (h0 + 2 < g))) ? 1 : 0;
        cnt += ((z3 < zg) || ((z3 == zg) && (h0 + 3 < g))) ? 1 : 0;
    }
#pragma unroll
    for (int off = 32; off >= 1; off >>= 1)
        cnt += __shfl_down(cnt, off);
    int rank = __shfl(cnt, 0);

    if (lane < 2) {
        const float4* src = reinterpret_cast<const float4*>(&pg);
        ((float4*)(gsorted + rank))[lane] = src[lane];
    }
}

// ---------------------------------------------------------------------------
// Kernel 2: one block = one wave = one 8x8 pixel tile, 1 pixel/thread,
// iterating front-to-back over ALL gaussians. No partials, no combine, no
// cross-block traffic. Grid (16,16) = 256 blocks = 1 wave/CU.
// Per 64-gaussian chunk: coalesced load (double-buffered in registers),
// stage to LDS, per-lane box/circle cull -> ballot -> ctz-walk in sorted
// order with broadcast LDS reads. Early-out when every pixel in the tile
// is saturated (T < 1e-6 => remaining contribution < 1e-6 << tolerance).
// ---------------------------------------------------------------------------
__global__ __launch_bounds__(64) void composite_tile_kernel(
    const PG* __restrict__ gsorted, const float* __restrict__ bg,
    float* __restrict__ out)
{
    __shared__ float4 sg[128]; // one 64-gaussian chunk (4 KiB)
    const int t = threadIdx.x;
    const int tx = blockIdx.x, ty = blockIdx.y;
    const int col = tx * 8 + (t & 7);
    const int row = ty * 8 + (t >> 3);

    // tile pixel-center bounds
    const float x0 = tx * 8 + 0.5f, x1 = x0 + 7.0f;
    const float y0 = ty * 8 + 0.5f, y1 = y0 + 7.0f;
    const float fpx = col + 0.5f;
    const float fpy = row + 0.5f;

    float T = 1.f, Cr = 0.f, Cg = 0.f, Cb = 0.f;

    const float4* src = (const float4*)gsorted;
    float4 n0 = src[2 * t];
    float4 n1 = src[2 * t + 1];

    for (int base = 0; base < NG; base += 64) {
        float4 g0 = n0, g1 = n1;
        sg[2 * t + 0] = g0;
        sg[2 * t + 1] = g1;
        if (base + 64 < NG) { // prefetch next chunk (uniform branch)
            n0 = src[2 * (base + 64 + t) + 0];
            n1 = src[2 * (base + 64 + t) + 1];
        }

        // lane t tests gaussian base+t against the tile
        union { float f; __half2 h; } ubr; ubr.f = g1.w;
        float r2 = __half2float(__high2half(ubr.h));
        float dxm = fmaxf(0.f, fmaxf(x0 - g0.x, g0.x - x1));
        float dym = fmaxf(0.f, fmaxf(y0 - g0.y, g0.y - y1));
        bool keep = (dxm * dxm + dym * dym) <= r2;
        unsigned long long mask = __ballot(keep);
        __syncthreads(); // single wave: compiles to lgkmcnt wait (+barrier)

        while (mask) {
            int i = (int)__builtin_ctzll(mask);
            mask &= (mask - 1);
            float4 f0 = sg[2 * i + 0]; // broadcast (same-address, no conflict)
            float4 f1 = sg[2 * i + 1];
            float dx = fpx - f0.x;
            float adx2 = f0.z * dx * dx;
            float bdx = f0.w * dx;
            float alpha = f1.y;
            union { float f; __half2 h; } urg; urg.f = f1.z;
            union { float f; __half2 h; } ubl; ubl.f = f1.w;
            float cr = __half2float(__low2half(urg.h));
            float cg = __half2float(__high2half(urg.h));
            float cb = __half2float(__low2half(ubl.h));

            float dy = fpy - f0.y;
            float p = fminf(fmaf(dy, fmaf(f1.x, dy, bdx), adx2), 0.f);
            float gv = exp2f(p);
            float a = fminf(0.99f, alpha * gv);
            float w = a * T;
            Cr = fmaf(w, cr, Cr); Cg = fmaf(w, cg, Cg); Cb = fmaf(w, cb, Cb);
            T = fmaf(-a, T, T);
        }

        if (__all(T < 1e-6f)) break; // tile saturated; error bound 1e-6
    }

    const int pix = row * IMG_W + col;
    out[pix * 3 + 0] = Cr + T * bg[0];
    out[pix * 3 + 1] = Cg + T * bg[1];
    out[pix * 3 + 2] = Cb + T * bg[2];
}

extern "C" void kernel_launch(void* const* d_in, const int* in_sizes, int n_in,
                              void* d_out, int out_size, void* d_ws, size_t ws_size,
                              hipStream_t stream)
{
    const float* mean      = (const float*)d_in[0];
    const float* qvec      = (const float*)d_in[1];
    const float* svec_raw  = (const float*)d_in[2];
    const float* color_raw = (const float*)d_in[3];
    const float* alpha_raw = (const float*)d_in[4];
    const float* bg        = (const float*)d_in[5];
    const float* viewmat   = (const float*)d_in[6];
    const float* intrins   = (const float*)d_in[7];
    PG* gsorted = (PG*)d_ws; // 64 KiB
    float* out = (float*)d_out;

    hipLaunchKernelGGL(prep_rank_kernel, dim3(NG * 64 / 256), dim3(256), 0,
                       stream, mean, qvec, svec_raw, color_raw, alpha_raw,
                       viewmat, intrins, gsorted);
    hipLaunchKernelGGL(composite_tile_kernel, dim3(16, 16), dim3(64), 0,
                       stream, gsorted, bg, out);
}

// Round 3
// 78.250 us; speedup vs baseline: 2.0584x; 1.4632x over previous
//
#include <hip/hip_runtime.h>
#include <hip/hip_fp16.h>
#include <math.h>

#define NG 2048
#define IMG_W 128
#define IMG_H 128
#define NPIX (IMG_W * IMG_H)
#define L2E 1.4426950408889634f

// 32-byte packed gaussian record = 2 x float4.
// A = -0.5*log2e*conic_a, B = -log2e*conic_b, C = -0.5*log2e*conic_c
// so power_log2 = A*dx^2 + B*dx*dy + C*dy^2 and g = exp2(min(power_log2,0)).
// f0 = (u, v, A, B); f1 = (C, alpha_f32, (cr,cg) half2, (cb, r2) half2)
// r2 = cull radius^2: skip gaussian for a tile if min dist^2 > r2.
struct __align__(16) PG {
    float u, v, A, B;
    float C, alpha;
    unsigned int rg;    // half2 (cr, cg)
    unsigned int b_r2;  // half2 (cb, r2)
};

// ---------------------------------------------------------------------------
// Kernel 1: per-gaussian preprocessing. 8 blocks x 256 threads.
// (round-0 verified version)
// ---------------------------------------------------------------------------
__global__ __launch_bounds__(256) void prep_kernel(
    const float* __restrict__ mean, const float* __restrict__ qvec,
    const float* __restrict__ svec_raw, const float* __restrict__ color_raw,
    const float* __restrict__ alpha_raw, const float* __restrict__ viewmat,
    const float* __restrict__ intrins, PG* __restrict__ graw,
    float* __restrict__ zbuf)
{
    const int g = blockIdx.x * 256 + threadIdx.x;
    if (g >= NG) return;

    const float fx = intrins[0], fy = intrins[1], cx = intrins[2], cy = intrins[3];
    const float R00 = viewmat[0], R01 = viewmat[1], R02 = viewmat[2],  t0 = viewmat[3];
    const float R10 = viewmat[4], R11 = viewmat[5], R12 = viewmat[6],  t1 = viewmat[7];
    const float R20 = viewmat[8], R21 = viewmat[9], R22 = viewmat[10], t2 = viewmat[11];

    float mx = mean[g * 3 + 0], my = mean[g * 3 + 1], mz = mean[g * 3 + 2];
    float x = R00 * mx + R01 * my + R02 * mz + t0;
    float y = R10 * mx + R11 * my + R12 * mz + t1;
    float z = R20 * mx + R21 * my + R22 * mz + t2;
    float zc = fmaxf(z, 0.001f);

    float qw = qvec[g * 4 + 0], qx = qvec[g * 4 + 1];
    float qy = qvec[g * 4 + 2], qz = qvec[g * 4 + 3];
    float qn = rsqrtf(qw * qw + qx * qx + qy * qy + qz * qz);
    qw *= qn; qx *= qn; qy *= qn; qz *= qn;
    float Rq00 = 1.f - 2.f * (qy * qy + qz * qz), Rq01 = 2.f * (qx * qy - qw * qz), Rq02 = 2.f * (qx * qz + qw * qy);
    float Rq10 = 2.f * (qx * qy + qw * qz), Rq11 = 1.f - 2.f * (qx * qx + qz * qz), Rq12 = 2.f * (qy * qz - qw * qx);
    float Rq20 = 2.f * (qx * qz - qw * qy), Rq21 = 2.f * (qy * qz + qw * qx), Rq22 = 1.f - 2.f * (qx * qx + qy * qy);

    float s0 = expf(svec_raw[g * 3 + 0]);
    float s1 = expf(svec_raw[g * 3 + 1]);
    float s2 = expf(svec_raw[g * 3 + 2]);
    float M00 = Rq00 * s0, M01 = Rq01 * s1, M02 = Rq02 * s2;
    float M10 = Rq10 * s0, M11 = Rq11 * s1, M12 = Rq12 * s2;
    float M20 = Rq20 * s0, M21 = Rq21 * s1, M22 = Rq22 * s2;

    float iz = 1.0f / zc;
    float J00 = fx * iz, J02 = -fx * x * iz * iz;
    float J11 = fy * iz, J12 = -fy * y * iz * iz;
    float T00 = J00 * R00 + J02 * R20;
    float T01 = J00 * R01 + J02 * R21;
    float T02 = J00 * R02 + J02 * R22;
    float T10 = J11 * R10 + J12 * R20;
    float T11 = J11 * R11 + J12 * R21;
    float T12 = J11 * R12 + J12 * R22;
    float TM00 = T00 * M00 + T01 * M10 + T02 * M20;
    float TM01 = T00 * M01 + T01 * M11 + T02 * M21;
    float TM02 = T00 * M02 + T01 * M12 + T02 * M22;
    float TM10 = T10 * M00 + T11 * M10 + T12 * M20;
    float TM11 = T10 * M01 + T11 * M11 + T12 * M21;
    float TM12 = T10 * M02 + T11 * M12 + T12 * M22;
    float a = TM00 * TM00 + TM01 * TM01 + TM02 * TM02 + 0.3f;
    float b = TM00 * TM10 + TM01 * TM11 + TM02 * TM12;
    float c = TM10 * TM10 + TM11 * TM11 + TM12 * TM12 + 0.3f;
    float det = a * c - b * b;
    float det_safe = fmaxf(det, 1e-8f);
    float inv_det = 1.0f / det_safe;
    bool valid = (z > 0.2f) && (det > 0.0f);
    float alpha = 1.0f / (1.0f + expf(-alpha_raw[g]));

    float conic_a = c * inv_det;
    float conic_b = -b * inv_det;
    float conic_c = a * inv_det;

    // cull radius^2 from conic lambda_min (THR = 24 log2-units; slack 1.05x)
    float half_tr = 0.5f * (conic_a + conic_c);
    float half_df = 0.5f * (conic_a - conic_c);
    float lam_min = half_tr - sqrtf(half_df * half_df + conic_b * conic_b);
    float r2 = (lam_min > 1e-20f) ? (1.05f * 2.0f * 24.0f / (L2E * lam_min)) : 3.0e38f;
    if (!valid) r2 = -1.0f; // skip always

    PG pg;
    pg.u = fx * x * iz + cx;
    pg.v = fy * y * iz + cy;
    pg.A = -0.5f * L2E * conic_a;
    pg.B = -L2E * conic_b;
    pg.C = -0.5f * L2E * conic_c;
    pg.alpha = alpha;
    float cr  = 1.0f / (1.0f + expf(-color_raw[g * 3 + 0]));
    float cg  = 1.0f / (1.0f + expf(-color_raw[g * 3 + 1]));
    float cbl = 1.0f / (1.0f + expf(-color_raw[g * 3 + 2]));
    __half2 hrg = __floats2half2_rn(cr, cg);
    pg.rg = *reinterpret_cast<unsigned int*>(&hrg);
    // (cb, r2) as half2; r2 > 65504 rounds to +inf -> always-keep (correctly
    // conservative); r2 = -1 -> always-skip (invalid gaussian).
    __half2 hbr = __halves2half2(__float2half_rn(cbl), __float2half_rn(r2));
    pg.b_r2 = *reinterpret_cast<unsigned int*>(&hbr);
    graw[g] = pg;
    zbuf[g] = z;
}

// ---------------------------------------------------------------------------
// Kernel 2: rank-count argsort + scatter. One wave per gaussian, float4 keys.
// rank[g] = #{h : z[h] < z[g] or (z[h]==z[g] and h<g)} -> stable permutation.
// (round-0 verified version)
// ---------------------------------------------------------------------------
__global__ __launch_bounds__(256) void rank_scatter_kernel(
    const float* __restrict__ zbuf, const PG* __restrict__ graw,
    PG* __restrict__ gsorted)
{
    const int g = (blockIdx.x * 256 + threadIdx.x) >> 6; // gaussian id
    const int lane = threadIdx.x & 63;
    const float zg = zbuf[g];
    const float4* z4 = (const float4*)zbuf;
    int cnt = 0;
#pragma unroll
    for (int k = 0; k < NG / 256; ++k) {
        int idx = k * 64 + lane;
        float4 zz = z4[idx];
        int h = idx * 4;
        cnt += ((zz.x < zg) || ((zz.x == zg) && (h + 0 < g))) ? 1 : 0;
        cnt += ((zz.y < zg) || ((zz.y == zg) && (h + 1 < g))) ? 1 : 0;
        cnt += ((zz.z < zg) || ((zz.z == zg) && (h + 2 < g))) ? 1 : 0;
        cnt += ((zz.w < zg) || ((zz.w == zg) && (h + 3 < g))) ? 1 : 0;
    }
#pragma unroll
    for (int off = 32; off >= 1; off >>= 1)
        cnt += __shfl_down(cnt, off);
    int rank = __shfl(cnt, 0);
    if (lane < 2) {
        ((float4*)(gsorted + rank))[lane] = ((const float4*)(graw + g))[lane];
    }
}

// ---------------------------------------------------------------------------
// Kernel 3: composite. One block = 256 threads = 4 waves per 8x8 tile; wave w
// composites sorted segment [w*512, (w+1)*512) in 8 register-resident chunks
// of 64 gaussians (one per lane). Cull -> ballot -> uniform mask; the walk
// broadcasts each kept gaussian's 8 words via v_readlane (uniform index, pure
// VALU, no LDS/memory latency). Per-wave early-out: once the wave's running T
// < 1e-6 on every pixel, remaining contribution to its partial is
// sum(a_i T_i) = T_break - T_end < 1e-6 << tolerance. Segments are merged
// in-order through LDS (no global partials, no fences, no extra kernel).
// Grid (16,16) = 256 blocks = 1 block/CU, 4 waves on the CU's 4 SIMDs.
// ---------------------------------------------------------------------------
__device__ __forceinline__ float rlf(float x, int i) {
    return __int_as_float(__builtin_amdgcn_readlane(__float_as_int(x), i));
}
__device__ __forceinline__ unsigned rlu(float x, int i) {
    return (unsigned)__builtin_amdgcn_readlane(__float_as_int(x), i);
}

__global__ __launch_bounds__(256) void composite_tile_kernel(
    const PG* __restrict__ gsorted, const float* __restrict__ bg,
    float* __restrict__ out)
{
    __shared__ float4 part[4][64];
    const int t = threadIdx.x;
    const int wave = t >> 6;
    const int lane = t & 63;
    const int tx = blockIdx.x, ty = blockIdx.y;
    const int col = tx * 8 + (lane & 7);
    const int row = ty * 8 + (lane >> 3);

    // tile pixel-center bounds
    const float x0 = tx * 8 + 0.5f, x1 = x0 + 7.0f;
    const float y0 = ty * 8 + 0.5f, y1 = y0 + 7.0f;
    const float fpx = col + 0.5f;
    const float fpy = row + 0.5f;

    float T = 1.f, Cr = 0.f, Cg = 0.f, Cb = 0.f;

    constexpr int SEG = NG / 4;        // 512 gaussians per wave
    constexpr int NCHUNK = SEG / 64;   // 8 chunks
    const float4* src = (const float4*)(gsorted + wave * SEG);
    float4 n0 = src[2 * lane + 0];
    float4 n1 = src[2 * lane + 1];

    for (int c = 0; c < NCHUNK; ++c) {
        float4 g0 = n0, g1 = n1;
        if (c + 1 < NCHUNK) { // uniform branch; prefetch next chunk
            n0 = src[2 * ((c + 1) * 64 + lane) + 0];
            n1 = src[2 * ((c + 1) * 64 + lane) + 1];
        }

        // lane tests its own gaussian against the tile (verdict per lane,
        // mask uniform across the wave)
        union { float f; __half2 h; } ubr; ubr.f = g1.w;
        float r2 = __half2float(__high2half(ubr.h));
        float dxm = fmaxf(0.f, fmaxf(x0 - g0.x, g0.x - x1));
        float dym = fmaxf(0.f, fmaxf(y0 - g0.y, g0.y - y1));
        unsigned long long mask = __ballot((dxm * dxm + dym * dym) <= r2);

        while (mask) {
            int i = (int)__builtin_ctzll(mask);
            mask &= (mask - 1);
            // broadcast gaussian i's record from lane i's registers
            float u  = rlf(g0.x, i), v  = rlf(g0.y, i);
            float A  = rlf(g0.z, i), B  = rlf(g0.w, i);
            float Cc = rlf(g1.x, i), al = rlf(g1.y, i);
            unsigned rgb = rlu(g1.z, i);
            unsigned brb = rlu(g1.w, i);
            union { unsigned u; __half2 h; } urg; urg.u = rgb;
            union { unsigned u; __half2 h; } ubl; ubl.u = brb;
            float cr = __half2float(__low2half(urg.h));
            float cg = __half2float(__high2half(urg.h));
            float cb = __half2float(__low2half(ubl.h));

            float dx = fpx - u;
            float adx2 = A * dx * dx;
            float bdx = B * dx;
            float dy = fpy - v;
            float p = fminf(fmaf(dy, fmaf(Cc, dy, bdx), adx2), 0.f);
            float gv = exp2f(p);
            float a = fminf(0.99f, al * gv);
            float w = a * T;
            Cr = fmaf(w, cr, Cr); Cg = fmaf(w, cg, Cg); Cb = fmaf(w, cb, Cb);
            T = fmaf(-a, T, T);
        }

        if (__all(T < 1e-6f)) break; // wave's remaining contribution < 1e-6
    }

    part[wave][lane] = make_float4(Cr, Cg, Cb, T);
    __syncthreads();

    if (wave == 0) {
        float4 p0 = part[0][lane];
        float4 p1 = part[1][lane];
        float4 p2 = part[2][lane];
        float4 p3 = part[3][lane];
        // in-order merge: C = C0 + T0*C1 + T0*T1*C2 + T0*T1*T2*C3
        float t01 = p0.w * p1.w;
        float t012 = t01 * p2.w;
        float R = p0.x + p0.w * p1.x + t01 * p2.x + t012 * p3.x;
        float G = p0.y + p0.w * p1.y + t01 * p2.y + t012 * p3.y;
        float Bc = p0.z + p0.w * p1.z + t01 * p2.z + t012 * p3.z;
        float Tt = t012 * p3.w;
        const int pix = row * IMG_W + col;
        out[pix * 3 + 0] = R + Tt * bg[0];
        out[pix * 3 + 1] = G + Tt * bg[1];
        out[pix * 3 + 2] = Bc + Tt * bg[2];
    }
}

extern "C" void kernel_launch(void* const* d_in, const int* in_sizes, int n_in,
                              void* d_out, int out_size, void* d_ws, size_t ws_size,
                              hipStream_t stream)
{
    const float* mean      = (const float*)d_in[0];
    const float* qvec      = (const float*)d_in[1];
    const float* svec_raw  = (const float*)d_in[2];
    const float* color_raw = (const float*)d_in[3];
    const float* alpha_raw = (const float*)d_in[4];
    const float* bg        = (const float*)d_in[5];
    const float* viewmat   = (const float*)d_in[6];
    const float* intrins   = (const float*)d_in[7];
    char* ws = (char*)d_ws;
    float* out = (float*)d_out;

    PG* graw    = (PG*)ws;                                    // 64 KiB
    float* zbuf = (float*)(ws + NG * sizeof(PG));             // 8 KiB
    PG* gsorted = (PG*)(ws + NG * sizeof(PG) + NG * sizeof(float)); // 64 KiB

    hipLaunchKernelGGL(prep_kernel, dim3(NG / 256), dim3(256), 0, stream,
                       mean, qvec, svec_raw, color_raw, alpha_raw, viewmat,
                       intrins, graw, zbuf);
    hipLaunchKernelGGL(rank_scatter_kernel, dim3(NG * 64 / 256), dim3(256),
                       0, stream, zbuf, graw, gsorted);
    hipLaunchKernelGGL(composite_tile_kernel, dim3(16, 16), dim3(256), 0,
                       stream, gsorted, bg, out);
}